// Round 4
// baseline (5260.888 us; speedup 1.0000x reference)
//
#include <hip/hip_runtime.h>

constexpr int kB = 256;
constexpr int kS = 512;
constexpr int kU = 256;

typedef _Float16 f16x2 __attribute__((ext_vector_type(2)));
typedef _Float16 f16x8 __attribute__((ext_vector_type(8)));
typedef float    f32x4 __attribute__((ext_vector_type(4)));

__device__ __forceinline__ float sigm(float x) {
    return 1.0f / (1.0f + __expf(-x));
}
__device__ __forceinline__ float tanh_fast(float x) {
    float ax = fabsf(x);
    float e = __expf(-2.0f * ax);
    float t = (1.0f - e) / (1.0f + e);
    return x < 0.0f ? -t : t;
}
__device__ __forceinline__ float dot2(unsigned w, unsigned h, float acc) {
    return __builtin_amdgcn_fdot2(__builtin_bit_cast(f16x2, w),
                                  __builtin_bit_cast(f16x2, h), acc, false);
}
__device__ __forceinline__ unsigned packh2(float lo, float hi) {
    f16x2 h; h.x = (_Float16)lo; h.y = (_Float16)hi;
    return __builtin_bit_cast(unsigned, h);
}

// ---------------------------------------------------------------------------
// ws layout:
//   [0 .. 5*8192) uint4 : B-fragment weights for hU,fW,iW,cW,oW (phase 1)
//     frag idx = mat*8192 + (nt*8 + kt)*64 + lane
//     lane l: n = nt*16 + (l&15), k0 = kt*32 + 8*(l>>4); holds W[k0..k0+7][n]
//   then (u32 idx 5*32768..) packed-pair tW, yW for phase 2
// ---------------------------------------------------------------------------
constexpr int kMatU32 = 32768;

__global__ __launch_bounds__(256) void convert_frag(
    const float* __restrict__ hU, const float* __restrict__ fW,
    const float* __restrict__ iW, const float* __restrict__ cW,
    const float* __restrict__ oW, uint4* __restrict__ wfrag)
{
    const int idx = blockIdx.x * 256 + threadIdx.x;   // 5*8192
    const int mat = idx >> 13;
    const int r   = idx & 8191;
    const int lane = r & 63;
    const int kt   = (r >> 6) & 7;
    const int nt   = r >> 9;
    const float* W = mat == 0 ? hU : mat == 1 ? fW : mat == 2 ? iW :
                     mat == 3 ? cW : oW;
    const int n  = nt * 16 + (lane & 15);
    const int k0 = kt * 32 + 8 * (lane >> 4);
    uint4 u;
    u.x = packh2(W[(k0 + 0) * kU + n], W[(k0 + 1) * kU + n]);
    u.y = packh2(W[(k0 + 2) * kU + n], W[(k0 + 3) * kU + n]);
    u.z = packh2(W[(k0 + 4) * kU + n], W[(k0 + 5) * kU + n]);
    u.w = packh2(W[(k0 + 6) * kU + n], W[(k0 + 7) * kU + n]);
    wfrag[idx] = u;
}

__global__ __launch_bounds__(256) void convert_pk(
    const float* __restrict__ tW, const float* __restrict__ yW,
    unsigned* __restrict__ wpk)
{
    const int idx = blockIdx.x * 256 + threadIdx.x;   // 2*32768
    const int mat = idx >> 15;
    const int r   = idx & (kMatU32 - 1);
    const int kp  = r >> 8;
    const int j   = r & 255;
    const float* W = mat == 0 ? tW : yW;
    wpk[idx] = packh2(W[(2 * kp) * kU + j], W[(2 * kp + 1) * kU + j]);
}

// ---------------------------------------------------------------------------
// Phase 1: sequential recurrence, MFMA + weight-residency version.
// 16 blocks x 1024 threads (16 waves). 16 batch rows per block (M=16).
// Wave w owns output columns [16w, 16w+16).
// LDS (dynamic 144 KB): hU B-frags (128 KB, resident) + hA + h1A A-tiles
//   in frag-linear layout (conflict-free ds_read_b128), single-buffered
//   (h1A read only before barrier1, written only after it).
// oW slice register-resident; fW,iW,cW streamed from L2 each step (384 KB).
// Writes g = o*h1 into d_out.
// ---------------------------------------------------------------------------
__global__ __launch_bounds__(1024) void rnn_phase1(
    const int* __restrict__ z,
    const float* __restrict__ hW, const float* __restrict__ hb,
    const float* __restrict__ fb, const float* __restrict__ ib,
    const float* __restrict__ cb, const float* __restrict__ ob,
    const float* __restrict__ h0,
    const uint4* wfrag,          // NOT restrict: forbid hoisting stream loads
    float* out)                  // NOT restrict: same reason
{
    extern __shared__ __align__(16) char smem[];
    uint4* hUl = (uint4*)smem;                 // 8192 uint4 = 131072 B
    char*  hAb  = smem + 131072;               // 8192 B  (A-frag linear)
    char*  h1Ab = smem + 139264;               // 8192 B  (A-frag linear)

    const int tid  = threadIdx.x;
    const int w    = tid >> 6;
    const int lane = tid & 63;
    const int m16  = lane & 15;
    const int g    = lane >> 4;
    const int b0   = blockIdx.x * 16;
    const int c    = w * 16 + m16;             // this lane's output column

    // stage hU frags into LDS (one-time)
    for (int i = tid; i < 8192; i += 1024) hUl[i] = wfrag[i];

    const uint4* ffrag = wfrag + 8192;
    const uint4* ifrag = wfrag + 16384;
    const uint4* cfrag = wfrag + 24576;
    const uint4* ofrag = wfrag + 32768;
    const int fidx = w * 512 + lane;           // (w*8+0)*64 + lane

    // register-resident oW slice (8 frags = 32 VGPRs)
    f16x8 oWr[8];
    #pragma unroll
    for (int kt = 0; kt < 8; ++kt)
        oWr[kt] = __builtin_bit_cast(f16x8, ofrag[fidx + kt * 64]);

    const float hbj = hb[c];
    const float fbj = fb[c], ibj = ib[c], cbj = cb[c], obj = ob[c];

    // A-frag write base for element (row=4g+r, k=c):
    //   byte = (c>>5)*1024 + ((c>>3)&3)*256 + (4g+r)*16 + (c&7)*2
    const int wb = (c >> 5) * 1024 + ((c >> 3) & 3) * 256 + g * 64 + (c & 7) * 2;

    // h1 master (fp32, rows 4g+r, column c) + LDS A-tile init
    float h1r[4];
    const float h0c = h0[c];
    #pragma unroll
    for (int r = 0; r < 4; ++r) {
        h1r[r] = h0c;
        *(_Float16*)(h1Ab + wb + r * 16) = (_Float16)h0c;
    }
    __syncthreads();

    size_t obase[4];
    #pragma unroll
    for (int r = 0; r < 4; ++r)
        obase[r] = (size_t)(b0 + 4 * g + r) * kS * kU + c;

    for (int t = 0; t < kS; ++t) {
        // ---- stream fW, iW (interleaved issue; arrival order matches use) ----
        uint4 fWu[8], iWu[8];
        #pragma unroll
        for (int kt = 0; kt < 8; ++kt) {
            fWu[kt] = ffrag[fidx + kt * 64];
            iWu[kt] = ifrag[fidx + kt * 64];
        }

        // ---- z + embedding gather (overlaps hU phase) ----
        float emb[4];
        #pragma unroll
        for (int r = 0; r < 4; ++r) {
            const int zt = (t == 0) ? 0 : (z[(b0 + 4 * g + r) * kS + t - 1] + 1);
            emb[r] = hW[zt * kU + c];
        }

        // ---- a = h1 @ hU  (A from LDS h1A, B from LDS hU) ----
        f32x4 acc = {0.f, 0.f, 0.f, 0.f};
        #pragma unroll
        for (int kt = 0; kt < 8; ++kt) {
            const f16x8 a = *(const f16x8*)(h1Ab + kt * 1024 + lane * 16);
            const f16x8 b = __builtin_bit_cast(f16x8, hUl[w * 512 + kt * 64 + lane]);
            acc = __builtin_amdgcn_mfma_f32_16x16x32_f16(a, b, acc, 0, 0, 0);
        }

        // ---- h = tanh(a + emb + hb) -> hA tile ----
        #pragma unroll
        for (int r = 0; r < 4; ++r) {
            const float hv = tanh_fast(acc[r] + emb[r] + hbj);
            *(_Float16*)(hAb + wb + r * 16) = (_Float16)hv;
        }
        __syncthreads();   // barrier 1: hA complete; h1A reads done

        // ---- stream cW (arrives while f/i pass computes) ----
        uint4 cWu[8];
        #pragma unroll
        for (int kt = 0; kt < 8; ++kt) cWu[kt] = cfrag[fidx + kt * 64];

        f32x4 af = {0.f,0.f,0.f,0.f}, ai = {0.f,0.f,0.f,0.f};
        f32x4 ac = {0.f,0.f,0.f,0.f}, ao = {0.f,0.f,0.f,0.f};

        // pass (f,i): one A-read feeds two mfmas
        #pragma unroll
        for (int kt = 0; kt < 8; ++kt) {
            const f16x8 a = *(const f16x8*)(hAb + kt * 1024 + lane * 16);
            af = __builtin_amdgcn_mfma_f32_16x16x32_f16(a, __builtin_bit_cast(f16x8, fWu[kt]), af, 0, 0, 0);
            ai = __builtin_amdgcn_mfma_f32_16x16x32_f16(a, __builtin_bit_cast(f16x8, iWu[kt]), ai, 0, 0, 0);
        }
        // pass (c,o): cW streamed, oW resident
        #pragma unroll
        for (int kt = 0; kt < 8; ++kt) {
            const f16x8 a = *(const f16x8*)(hAb + kt * 1024 + lane * 16);
            ac = __builtin_amdgcn_mfma_f32_16x16x32_f16(a, __builtin_bit_cast(f16x8, cWu[kt]), ac, 0, 0, 0);
            ao = __builtin_amdgcn_mfma_f32_16x16x32_f16(a, oWr[kt], ao, 0, 0, 0);
        }

        // ---- activations, state update, g output, next h1 tile ----
        #pragma unroll
        for (int r = 0; r < 4; ++r) {
            const float f  = sigm(af[r] + fbj);
            const float i_ = sigm(ai[r] + ibj);
            const float cc = tanh_fast(ac[r] + cbj);
            const float o  = sigm(ao[r] + obj);
            h1r[r] = h1r[r] * f + cc * i_;
            out[obase[r] + (size_t)t * kU] = o * h1r[r];
            *(_Float16*)(h1Ab + wb + r * 16) = (_Float16)h1r[r];
        }
        __syncthreads();   // barrier 2: h1A writes visible for next step
    }
}

// ---------------------------------------------------------------------------
// Phase 2: output head (unchanged). 4096 blocks x 256 threads.
// ---------------------------------------------------------------------------
__global__ __launch_bounds__(256) void rnn_phase2(
    const float* __restrict__ tb, const float* __restrict__ yb,
    const unsigned* __restrict__ wpk,
    float* __restrict__ out)
{
    __shared__ float    lg[32][kU];
    __shared__ unsigned xpk[32][kU / 2];

    const unsigned* __restrict__ tWpk = wpk;
    const unsigned* __restrict__ yWpk = wpk + kMatU32;

    const int c = threadIdx.x;
    const size_t rowbase = (size_t)blockIdx.x * 32;

    {
        const float4* src = (const float4*)&out[rowbase * kU];
        float4* dst = (float4*)&lg[0][0];
        #pragma unroll
        for (int i = 0; i < 8; ++i) dst[i * 256 + c] = src[i * 256 + c];
    }
    __syncthreads();

    #pragma unroll
    for (int i = 0; i < 16; ++i) {
        const int flat = i * 256 + c;
        const int r = flat >> 7, kp = flat & 127;
        xpk[r][kp] = packh2(lg[r][2 * kp], lg[r][2 * kp + 1]);
    }
    __syncthreads();

    float acc[32];

    {
        const float tbc = tb[c];
        #pragma unroll
        for (int r = 0; r < 32; ++r) acc[r] = tbc;
    }
    #pragma unroll 2
    for (int kp4 = 0; kp4 < 32; ++kp4) {
        const unsigned w0 = tWpk[(4 * kp4 + 0) * kU + c];
        const unsigned w1 = tWpk[(4 * kp4 + 1) * kU + c];
        const unsigned w2 = tWpk[(4 * kp4 + 2) * kU + c];
        const unsigned w3 = tWpk[(4 * kp4 + 3) * kU + c];
        #pragma unroll
        for (int r = 0; r < 32; ++r) {
            const uint4 g4 = *(const uint4*)&xpk[r][4 * kp4];
            acc[r] = dot2(w0, g4.x, acc[r]);
            acc[r] = dot2(w1, g4.y, acc[r]);
            acc[r] = dot2(w2, g4.z, acc[r]);
            acc[r] = dot2(w3, g4.w, acc[r]);
        }
    }
    __syncthreads();

    #pragma unroll
    for (int r = 0; r < 32; ++r) {
        const float th = tanh_fast(acc[r]);
        const float hh = __shfl_down(th, 1, 64);
        if ((c & 1) == 0) xpk[r][c >> 1] = packh2(th, hh);
    }
    __syncthreads();

    {
        const float ybc = yb[c];
        #pragma unroll
        for (int r = 0; r < 32; ++r) acc[r] = ybc;
    }
    #pragma unroll 2
    for (int kp4 = 0; kp4 < 32; ++kp4) {
        const unsigned w0 = yWpk[(4 * kp4 + 0) * kU + c];
        const unsigned w1 = yWpk[(4 * kp4 + 1) * kU + c];
        const unsigned w2 = yWpk[(4 * kp4 + 2) * kU + c];
        const unsigned w3 = yWpk[(4 * kp4 + 3) * kU + c];
        #pragma unroll
        for (int r = 0; r < 32; ++r) {
            const uint4 t4 = *(const uint4*)&xpk[r][4 * kp4];
            acc[r] = dot2(w0, t4.x, acc[r]);
            acc[r] = dot2(w1, t4.y, acc[r]);
            acc[r] = dot2(w2, t4.z, acc[r]);
            acc[r] = dot2(w3, t4.w, acc[r]);
        }
    }

    #pragma unroll
    for (int r = 0; r < 32; ++r) lg[r][c] = acc[r];
    __syncthreads();

    const int wv = c >> 6, lane = c & 63;
    for (int q = 0; q < 8; ++q) {
        const int r = wv * 8 + q;
        const float4 v = *(const float4*)&lg[r][lane * 4];
        float m = fmaxf(fmaxf(v.x, v.y), fmaxf(v.z, v.w));
        #pragma unroll
        for (int off = 32; off > 0; off >>= 1) m = fmaxf(m, __shfl_xor(m, off, 64));
        const float e0 = __expf(v.x - m), e1 = __expf(v.y - m);
        const float e2 = __expf(v.z - m), e3 = __expf(v.w - m);
        float s = e0 + e1 + e2 + e3;
        #pragma unroll
        for (int off = 32; off > 0; off >>= 1) s += __shfl_xor(s, off, 64);
        const float inv = 1.0f / s;
        float4 o4; o4.x = e0 * inv; o4.y = e1 * inv; o4.z = e2 * inv; o4.w = e3 * inv;
        *(float4*)&out[(rowbase + r) * kU + lane * 4] = o4;
    }
}

extern "C" void kernel_launch(void* const* d_in, const int* in_sizes, int n_in,
                              void* d_out, int out_size, void* d_ws, size_t ws_size,
                              hipStream_t stream) {
    const int*   z  = (const int*)d_in[0];
    const float* hW = (const float*)d_in[1];
    const float* hU = (const float*)d_in[2];
    const float* hb = (const float*)d_in[3];
    const float* fW = (const float*)d_in[4];
    const float* fb = (const float*)d_in[5];
    const float* iW = (const float*)d_in[6];
    const float* ib = (const float*)d_in[7];
    const float* cW = (const float*)d_in[8];
    const float* cb = (const float*)d_in[9];
    const float* oW = (const float*)d_in[10];
    const float* ob = (const float*)d_in[11];
    const float* tW = (const float*)d_in[12];
    const float* tb = (const float*)d_in[13];
    const float* yW = (const float*)d_in[14];
    const float* yb = (const float*)d_in[15];
    const float* h0 = (const float*)d_in[16];
    float* out = (float*)d_out;

    uint4*    wfrag = (uint4*)d_ws;                   // 5*8192 uint4 = 640 KB
    unsigned* wpk   = (unsigned*)d_ws + 5 * kMatU32;  // tW, yW packed pairs

    // allow 144 KB dynamic LDS (host-side attribute; not a stream op)
    static bool attr_done = false;
    if (!attr_done) {
        hipFuncSetAttribute((const void*)rnn_phase1,
                            hipFuncAttributeMaxDynamicSharedMemorySize, 147456);
        attr_done = true;
    }

    convert_frag<<<dim3(5 * 8192 / 256), dim3(256), 0, stream>>>(
        hU, fW, iW, cW, oW, wfrag);
    convert_pk<<<dim3(2 * kMatU32 / 256), dim3(256), 0, stream>>>(tW, yW, wpk);
    rnn_phase1<<<dim3(kB / 16), dim3(1024), 147456, stream>>>(
        z, hW, hb, fb, ib, cb, ob, h0, wfrag, out);
    rnn_phase2<<<dim3((kB * kS) / 32), dim3(256), 0, stream>>>(
        tb, yb, wpk, out);
}

// Round 5
// 3430.343 us; speedup vs baseline: 1.5336x; 1.5336x over previous
//
#include <hip/hip_runtime.h>

constexpr int kB = 256;
constexpr int kS = 512;
constexpr int kU = 256;

typedef _Float16 f16x2 __attribute__((ext_vector_type(2)));
typedef _Float16 f16x8 __attribute__((ext_vector_type(8)));
typedef float    f32x4 __attribute__((ext_vector_type(4)));

__device__ __forceinline__ float sigm(float x) {
    return 1.0f / (1.0f + __expf(-x));
}
__device__ __forceinline__ float tanh_fast(float x) {
    float ax = fabsf(x);
    float e = __expf(-2.0f * ax);
    float t = (1.0f - e) / (1.0f + e);
    return x < 0.0f ? -t : t;
}
__device__ __forceinline__ float dot2(unsigned w, unsigned h, float acc) {
    return __builtin_amdgcn_fdot2(__builtin_bit_cast(f16x2, w),
                                  __builtin_bit_cast(f16x2, h), acc, false);
}
__device__ __forceinline__ unsigned packh2(float lo, float hi) {
    f16x2 h; h.x = (_Float16)lo; h.y = (_Float16)hi;
    return __builtin_bit_cast(unsigned, h);
}
// byte offset of element (row m, col k) inside a frag-linear 16x256 fp16 A-tile
// (frag kt at kt*1024, lane l holds row l&15, k = kt*32 + 8*(l>>4) + i)
__device__ __forceinline__ int afrag_byte(int m, int k) {
    return (k >> 5) * 1024 + ((m & 15) + 16 * ((k >> 3) & 3)) * 16 + (k & 7) * 2;
}

// ---------------------------------------------------------------------------
// ws layout (bytes):
//   [0, 640K)          uint4 B-frag weights hU,fW,iW,cW,oW (idx = mat*8192 + (nt*8+kt)*64 + lane)
//   [640K, 896K)       packed-pair tW,yW for phase 2
//   [896K, 898K)       flags: 32 ints, stride-16 dwords (per pair*2+half)
//   [898K, 1154K)      xbuf: per (pair*2+half): 2 parities x 1024 dwords (4 KB h1 slices)
// ---------------------------------------------------------------------------
constexpr int    kMatU32   = 32768;
constexpr size_t kWpkOffB  = (size_t)5 * 8192 * 16;      // 655360
constexpr size_t kFlagOffB = kWpkOffB + 2 * kMatU32 * 4; // 917504
constexpr size_t kXbufOffB = kFlagOffB + 2048;           // 919552

__global__ __launch_bounds__(256) void convert_frag(
    const float* __restrict__ hU, const float* __restrict__ fW,
    const float* __restrict__ iW, const float* __restrict__ cW,
    const float* __restrict__ oW, uint4* __restrict__ wfrag)
{
    const int idx = blockIdx.x * 256 + threadIdx.x;   // 5*8192
    const int mat = idx >> 13;
    const int r   = idx & 8191;
    const int lane = r & 63;
    const int kt   = (r >> 6) & 7;
    const int nt   = r >> 9;
    const float* W = mat == 0 ? hU : mat == 1 ? fW : mat == 2 ? iW :
                     mat == 3 ? cW : oW;
    const int n  = nt * 16 + (lane & 15);
    const int k0 = kt * 32 + 8 * (lane >> 4);
    uint4 u;
    u.x = packh2(W[(k0 + 0) * kU + n], W[(k0 + 1) * kU + n]);
    u.y = packh2(W[(k0 + 2) * kU + n], W[(k0 + 3) * kU + n]);
    u.z = packh2(W[(k0 + 4) * kU + n], W[(k0 + 5) * kU + n]);
    u.w = packh2(W[(k0 + 6) * kU + n], W[(k0 + 7) * kU + n]);
    wfrag[idx] = u;
}

__global__ __launch_bounds__(256) void convert_pk(
    const float* __restrict__ tW, const float* __restrict__ yW,
    unsigned* __restrict__ wpk)
{
    const int idx = blockIdx.x * 256 + threadIdx.x;   // 2*32768
    const int mat = idx >> 15;
    const int r   = idx & (kMatU32 - 1);
    const int kp  = r >> 8;
    const int j   = r & 255;
    const float* W = mat == 0 ? tW : yW;
    wpk[idx] = packh2(W[(2 * kp) * kU + j], W[(2 * kp + 1) * kU + j]);
}

// ---------------------------------------------------------------------------
// Phase 1: sequential recurrence, weight-resident, CU-pair cooperative.
// 32 blocks x 1024 threads. Pair p = blocks {2p, 2p+1}, rows b0 = 16p.
// Block half owns output cols [128*half, 128*half+128) of all gate matrices
// (in VGPRs: 64/wave) and holds FULL hU in LDS (128 KB). h is computed
// redundantly (full width) by both blocks; only h1 (16x128 fp16 = 4 KB) is
// exchanged per step via agent-scope atomics + release/acquire flag.
// Waves: hU phase: wave w -> col tile w (0..15). Gate phase: wave 2q: (f,i)
// for local tile q; wave 2q+1: (c,o) tile q. Even waves own h1 master (fp32).
// ---------------------------------------------------------------------------
__global__ __launch_bounds__(1024) void rnn_phase1(
    const int* __restrict__ z,
    const float* __restrict__ hW, const float* __restrict__ hb,
    const float* __restrict__ fb, const float* __restrict__ ib,
    const float* __restrict__ cb, const float* __restrict__ ob,
    const float* __restrict__ h0,
    const uint4* __restrict__ wfrag,
    int* flags, unsigned* xbuf,
    float* __restrict__ out)
{
    extern __shared__ __align__(16) char smem[];
    uint4* hUl  = (uint4*)smem;                // 131072 B (full hU, B-frags)
    char*  h1Ab = smem + 131072;               // 8192 B (h1 A-tile, K=256)
    char*  hAb  = smem + 139264;               // 8192 B (h A-tile, K=256)
    float* cscr = (float*)(smem + 147456);     // 8192 B (c-gate scratch)

    const int tid  = threadIdx.x;
    const int w    = tid >> 6;
    const int lane = tid & 63;
    const int m16  = lane & 15;
    const int g    = lane >> 4;
    const int pair = blockIdx.x >> 1;
    const int half = blockIdx.x & 1;
    const int b0   = pair * 16;
    const int cb_own = half * 128;
    const int cb_par = 128 - cb_own;
    const int q    = w >> 1;                   // gate col tile (local 0..7)
    const bool evenw = (w & 1) == 0;
    const int ch   = w * 16 + m16;             // hU-phase column (global)
    const int cg   = cb_own + 16 * q + m16;    // gate-phase column (global)

    int* oflag = flags + (pair * 2 + half) * 16;
    int* pflag = flags + (pair * 2 + (1 - half)) * 16;
    unsigned* xsend = xbuf + (size_t)(pair * 2 + half) * 2048;
    unsigned* xrecv = xbuf + (size_t)(pair * 2 + (1 - half)) * 2048;

    // one-time: full hU into LDS
    for (int i = tid; i < 8192; i += 1024) hUl[i] = wfrag[i];

    // gate weights into registers: even wave: fW(1), iW(2); odd: cW(3), oW(4)
    const int ntg = half * 8 + q;              // global col tile of gate slice
    f16x8 wA[8], wB[8];
    {
        const int matA = evenw ? 1 : 3;
        const int matB = evenw ? 2 : 4;
        #pragma unroll
        for (int kt = 0; kt < 8; ++kt) {
            wA[kt] = __builtin_bit_cast(f16x8, wfrag[matA * 8192 + (ntg * 8 + kt) * 64 + lane]);
            wB[kt] = __builtin_bit_cast(f16x8, wfrag[matB * 8192 + (ntg * 8 + kt) * 64 + lane]);
        }
    }

    const float hbv = hb[ch];
    const float bA  = (evenw ? fb : cb)[cg];
    const float bB  = (evenw ? ib : ob)[cg];

    // init h1 master (even waves) + full h1A tile
    float h1m[4] = {0.f, 0.f, 0.f, 0.f};
    if (evenw) {
        const float v = h0[cg];
        #pragma unroll
        for (int r = 0; r < 4; ++r) h1m[r] = v;
    }
    for (int i = tid; i < 16 * kU; i += 1024) {
        const int m = i >> 8, k = i & 255;
        *(_Float16*)(h1Ab + afrag_byte(m, k)) = (_Float16)h0[k];
    }
    __syncthreads();

    for (int t = 0; t < kS; ++t) {
        const bool last = (t == kS - 1);

        // early: z + embedding loads (for hU col ch, rows 4g+r)
        float emb[4];
        #pragma unroll
        for (int r = 0; r < 4; ++r) {
            const int m  = 4 * g + r;
            const int zt = (t == 0) ? 0 : (z[(b0 + m) * kS + t - 1] + 1);
            emb[r] = hW[zt * kU + ch];
        }

        // (0) odd waves: receive partner h1 slice of step t-1
        if (!evenw && t > 0) {
            while (__hip_atomic_load(pflag, __ATOMIC_ACQUIRE,
                                     __HIP_MEMORY_SCOPE_AGENT) < t) {}
            unsigned* src = xrecv + (size_t)((t - 1) & 1) * 1024 + (q * 64 + lane) * 2;
            const unsigned d0 = __hip_atomic_load(src + 0, __ATOMIC_RELAXED, __HIP_MEMORY_SCOPE_AGENT);
            const unsigned d1 = __hip_atomic_load(src + 1, __ATOMIC_RELAXED, __HIP_MEMORY_SCOPE_AGENT);
            const int kp = cb_par + 16 * q + m16;
            const f16x2 p0 = __builtin_bit_cast(f16x2, d0);
            const f16x2 p1 = __builtin_bit_cast(f16x2, d1);
            *(_Float16*)(h1Ab + afrag_byte(4 * g + 0, kp)) = p0.x;
            *(_Float16*)(h1Ab + afrag_byte(4 * g + 1, kp)) = p0.y;
            *(_Float16*)(h1Ab + afrag_byte(4 * g + 2, kp)) = p1.x;
            *(_Float16*)(h1Ab + afrag_byte(4 * g + 3, kp)) = p1.y;
        }

        // (1) hU: own-half K first (valid since barrier F of prev step)
        f32x4 acc = {0.f, 0.f, 0.f, 0.f};
        #pragma unroll
        for (int k4 = 0; k4 < 4; ++k4) {
            const int kt = half * 4 + k4;
            const f16x8 a = *(const f16x8*)(h1Ab + kt * 1024 + lane * 16);
            const f16x8 b = __builtin_bit_cast(f16x8, hUl[(w * 8 + kt) * 64 + lane]);
            acc = __builtin_amdgcn_mfma_f32_16x16x32_f16(a, b, acc, 0, 0, 0);
        }
        __syncthreads();   // H: partner h1A half unpacked

        // (2) hU: partner-half K; h = tanh(..); pack hA tile (full width)
        #pragma unroll
        for (int k4 = 0; k4 < 4; ++k4) {
            const int kt = (1 - half) * 4 + k4;
            const f16x8 a = *(const f16x8*)(h1Ab + kt * 1024 + lane * 16);
            const f16x8 b = __builtin_bit_cast(f16x8, hUl[(w * 8 + kt) * 64 + lane]);
            acc = __builtin_amdgcn_mfma_f32_16x16x32_f16(a, b, acc, 0, 0, 0);
        }
        #pragma unroll
        for (int r = 0; r < 4; ++r) {
            const float hv = tanh_fast(acc[r] + emb[r] + hbv);
            *(_Float16*)(hAb + afrag_byte(4 * g + r, ch)) = (_Float16)hv;
        }
        __syncthreads();   // B: hA complete

        // (3) gates: 8 kt x 2 mfma; activations
        f32x4 aA = {0.f,0.f,0.f,0.f}, aB = {0.f,0.f,0.f,0.f};
        #pragma unroll
        for (int kt = 0; kt < 8; ++kt) {
            const f16x8 a = *(const f16x8*)(hAb + kt * 1024 + lane * 16);
            aA = __builtin_amdgcn_mfma_f32_16x16x32_f16(a, wA[kt], aA, 0, 0, 0);
            aB = __builtin_amdgcn_mfma_f32_16x16x32_f16(a, wB[kt], aB, 0, 0, 0);
        }
        float vA[4], vB[4];
        if (evenw) {
            #pragma unroll
            for (int r = 0; r < 4; ++r) { vA[r] = sigm(aA[r] + bA); vB[r] = sigm(aB[r] + bB); }
        } else {
            #pragma unroll
            for (int r = 0; r < 4; ++r) { vA[r] = tanh_fast(aA[r] + bA); vB[r] = sigm(aB[r] + bB); }
            #pragma unroll
            for (int r = 0; r < 4; ++r) cscr[q * 256 + lane * 4 + r] = vA[r];
        }
        __syncthreads();   // D: c-gate scratch ready

        // (4) even waves: h1 update, own h1A half, send slice to partner
        if (evenw) {
            #pragma unroll
            for (int r = 0; r < 4; ++r) {
                const float cr = cscr[q * 256 + lane * 4 + r];
                h1m[r] = h1m[r] * vA[r] + cr * vB[r];
            }
            #pragma unroll
            for (int r = 0; r < 4; ++r)
                *(_Float16*)(h1Ab + afrag_byte(4 * g + r, cg)) = (_Float16)h1m[r];
            if (!last) {
                unsigned* dst = xsend + (size_t)(t & 1) * 1024 + (q * 64 + lane) * 2;
                __hip_atomic_store(dst + 0, packh2(h1m[0], h1m[1]), __ATOMIC_RELAXED, __HIP_MEMORY_SCOPE_AGENT);
                __hip_atomic_store(dst + 1, packh2(h1m[2], h1m[3]), __ATOMIC_RELAXED, __HIP_MEMORY_SCOPE_AGENT);
            }
        }
        __syncthreads();   // F: h1A own half written; sends retired (vmcnt drain)

        // (5) publish flag; odd waves: g = o*h1 output
        if (tid == 0 && !last)
            __hip_atomic_store(oflag, t + 1, __ATOMIC_RELEASE, __HIP_MEMORY_SCOPE_AGENT);
        if (!evenw) {
            #pragma unroll
            for (int r = 0; r < 4; ++r) {
                const int m = 4 * g + r;
                const float h1f = (float)*(const _Float16*)(h1Ab + afrag_byte(m, cg));
                out[((size_t)(b0 + m) * kS + t) * kU + cg] = vB[r] * h1f;
            }
        }
    }
}

// ---------------------------------------------------------------------------
// Phase 2: output head (round-2 version). 4096 blocks x 256 threads.
// ---------------------------------------------------------------------------
__global__ __launch_bounds__(256) void rnn_phase2(
    const float* __restrict__ tb, const float* __restrict__ yb,
    const unsigned* __restrict__ wpk,
    float* __restrict__ out)
{
    __shared__ float    lg[32][kU];
    __shared__ unsigned xpk[32][kU / 2];

    const unsigned* __restrict__ tWpk = wpk;
    const unsigned* __restrict__ yWpk = wpk + kMatU32;

    const int c = threadIdx.x;
    const size_t rowbase = (size_t)blockIdx.x * 32;

    {
        const float4* src = (const float4*)&out[rowbase * kU];
        float4* dst = (float4*)&lg[0][0];
        #pragma unroll
        for (int i = 0; i < 8; ++i) dst[i * 256 + c] = src[i * 256 + c];
    }
    __syncthreads();

    #pragma unroll
    for (int i = 0; i < 16; ++i) {
        const int flat = i * 256 + c;
        const int r = flat >> 7, kp = flat & 127;
        xpk[r][kp] = packh2(lg[r][2 * kp], lg[r][2 * kp + 1]);
    }
    __syncthreads();

    float acc[32];

    {
        const float tbc = tb[c];
        #pragma unroll
        for (int r = 0; r < 32; ++r) acc[r] = tbc;
    }
    #pragma unroll 2
    for (int kp4 = 0; kp4 < 32; ++kp4) {
        const unsigned w0 = tWpk[(4 * kp4 + 0) * kU + c];
        const unsigned w1 = tWpk[(4 * kp4 + 1) * kU + c];
        const unsigned w2 = tWpk[(4 * kp4 + 2) * kU + c];
        const unsigned w3 = tWpk[(4 * kp4 + 3) * kU + c];
        #pragma unroll
        for (int r = 0; r < 32; ++r) {
            const uint4 g4 = *(const uint4*)&xpk[r][4 * kp4];
            acc[r] = dot2(w0, g4.x, acc[r]);
            acc[r] = dot2(w1, g4.y, acc[r]);
            acc[r] = dot2(w2, g4.z, acc[r]);
            acc[r] = dot2(w3, g4.w, acc[r]);
        }
    }
    __syncthreads();

    #pragma unroll
    for (int r = 0; r < 32; ++r) {
        const float th = tanh_fast(acc[r]);
        const float hh = __shfl_down(th, 1, 64);
        if ((c & 1) == 0) xpk[r][c >> 1] = packh2(th, hh);
    }
    __syncthreads();

    {
        const float ybc = yb[c];
        #pragma unroll
        for (int r = 0; r < 32; ++r) acc[r] = ybc;
    }
    #pragma unroll 2
    for (int kp4 = 0; kp4 < 32; ++kp4) {
        const unsigned w0 = yWpk[(4 * kp4 + 0) * kU + c];
        const unsigned w1 = yWpk[(4 * kp4 + 1) * kU + c];
        const unsigned w2 = yWpk[(4 * kp4 + 2) * kU + c];
        const unsigned w3 = yWpk[(4 * kp4 + 3) * kU + c];
        #pragma unroll
        for (int r = 0; r < 32; ++r) {
            const uint4 t4 = *(const uint4*)&xpk[r][4 * kp4];
            acc[r] = dot2(w0, t4.x, acc[r]);
            acc[r] = dot2(w1, t4.y, acc[r]);
            acc[r] = dot2(w2, t4.z, acc[r]);
            acc[r] = dot2(w3, t4.w, acc[r]);
        }
    }

    #pragma unroll
    for (int r = 0; r < 32; ++r) lg[r][c] = acc[r];
    __syncthreads();

    const int wv = c >> 6, lane = c & 63;
    for (int qq = 0; qq < 8; ++qq) {
        const int r = wv * 8 + qq;
        const float4 v = *(const float4*)&lg[r][lane * 4];
        float m = fmaxf(fmaxf(v.x, v.y), fmaxf(v.z, v.w));
        #pragma unroll
        for (int off = 32; off > 0; off >>= 1) m = fmaxf(m, __shfl_xor(m, off, 64));
        const float e0 = __expf(v.x - m), e1 = __expf(v.y - m);
        const float e2 = __expf(v.z - m), e3 = __expf(v.w - m);
        float s = e0 + e1 + e2 + e3;
        #pragma unroll
        for (int off = 32; off > 0; off >>= 1) s += __shfl_xor(s, off, 64);
        const float inv = 1.0f / s;
        float4 o4; o4.x = e0 * inv; o4.y = e1 * inv; o4.z = e2 * inv; o4.w = e3 * inv;
        *(float4*)&out[(rowbase + r) * kU + lane * 4] = o4;
    }
}

extern "C" void kernel_launch(void* const* d_in, const int* in_sizes, int n_in,
                              void* d_out, int out_size, void* d_ws, size_t ws_size,
                              hipStream_t stream) {
    const int*   z  = (const int*)d_in[0];
    const float* hW = (const float*)d_in[1];
    const float* hU = (const float*)d_in[2];
    const float* hb = (const float*)d_in[3];
    const float* fW = (const float*)d_in[4];
    const float* fb = (const float*)d_in[5];
    const float* iW = (const float*)d_in[6];
    const float* ib = (const float*)d_in[7];
    const float* cW = (const float*)d_in[8];
    const float* cb = (const float*)d_in[9];
    const float* oW = (const float*)d_in[10];
    const float* ob = (const float*)d_in[11];
    const float* tW = (const float*)d_in[12];
    const float* tb = (const float*)d_in[13];
    const float* yW = (const float*)d_in[14];
    const float* yb = (const float*)d_in[15];
    const float* h0 = (const float*)d_in[16];
    float* out = (float*)d_out;

    uint4*    wfrag = (uint4*)d_ws;
    unsigned* wpk   = (unsigned*)((char*)d_ws + kWpkOffB);
    int*      flags = (int*)((char*)d_ws + kFlagOffB);
    unsigned* xbuf  = (unsigned*)((char*)d_ws + kXbufOffB);

    // allow 152 KB dynamic LDS (host-side attr; idempotent, deterministic)
    hipFuncSetAttribute((const void*)rnn_phase1,
                        hipFuncAttributeMaxDynamicSharedMemorySize, 155648);

    // reset exchange flags for this call (replay-safe)
    hipMemsetAsync((char*)d_ws + kFlagOffB, 0, 2048, stream);

    convert_frag<<<dim3(5 * 8192 / 256), dim3(256), 0, stream>>>(
        hU, fW, iW, cW, oW, wfrag);
    convert_pk<<<dim3(2 * kMatU32 / 256), dim3(256), 0, stream>>>(tW, yW, wpk);
    rnn_phase1<<<dim3(kB / 8), dim3(1024), 155648, stream>>>(
        z, hW, hb, fb, ib, cb, ob, h0, wfrag, flags, xbuf, out);
    rnn_phase2<<<dim3((kB * kS) / 32), dim3(256), 0, stream>>>(
        tb, yb, wpk, out);
}

// Round 6
// 3377.254 us; speedup vs baseline: 1.5577x; 1.0157x over previous
//
#include <hip/hip_runtime.h>

constexpr int kB = 256;
constexpr int kS = 512;
constexpr int kU = 256;

typedef _Float16 f16x2 __attribute__((ext_vector_type(2)));
typedef _Float16 f16x8 __attribute__((ext_vector_type(8)));
typedef float    f32x4 __attribute__((ext_vector_type(4)));

__device__ __forceinline__ float sigm(float x) {
    return 1.0f / (1.0f + __expf(-x));
}
__device__ __forceinline__ float tanh_fast(float x) {
    float ax = fabsf(x);
    float e = __expf(-2.0f * ax);
    float t = (1.0f - e) / (1.0f + e);
    return x < 0.0f ? -t : t;
}
__device__ __forceinline__ float dot2(unsigned w, unsigned h, float acc) {
    return __builtin_amdgcn_fdot2(__builtin_bit_cast(f16x2, w),
                                  __builtin_bit_cast(f16x2, h), acc, false);
}
__device__ __forceinline__ unsigned packh2(float lo, float hi) {
    f16x2 h; h.x = (_Float16)lo; h.y = (_Float16)hi;
    return __builtin_bit_cast(unsigned, h);
}
// byte offset of element (row m, col k) inside a frag-linear 16x256 fp16 A-tile
// (frag kt at kt*1024; lane l holds row l&15, k = kt*32 + 8*(l>>4) + i)
__device__ __forceinline__ int afrag_byte(int m, int k) {
    return (k >> 5) * 1024 + ((m & 15) + 16 * ((k >> 3) & 3)) * 16 + (k & 7) * 2;
}

// ---------------------------------------------------------------------------
// ws layout:
//   [0, 512K)   uint4 B-frag weights hU,fW,iW,cW (idx = mat*8192 + (nt*8+kt)*64 + lane)
//   [512K, 896K) packed-pair oW,tW,yW for phase 2 (u32 idx mat*32768 + kp*256 + j)
// ---------------------------------------------------------------------------
constexpr int kMatU32 = 32768;

__global__ __launch_bounds__(256) void convert_frag(
    const float* __restrict__ hU, const float* __restrict__ fW,
    const float* __restrict__ iW, const float* __restrict__ cW,
    uint4* __restrict__ wfrag)
{
    const int idx = blockIdx.x * 256 + threadIdx.x;   // 4*8192
    const int mat = idx >> 13;
    const int r   = idx & 8191;
    const int lane = r & 63;
    const int kt   = (r >> 6) & 7;
    const int nt   = r >> 9;
    const float* W = mat == 0 ? hU : mat == 1 ? fW : mat == 2 ? iW : cW;
    const int n  = nt * 16 + (lane & 15);
    const int k0 = kt * 32 + 8 * (lane >> 4);
    uint4 u;
    u.x = packh2(W[(k0 + 0) * kU + n], W[(k0 + 1) * kU + n]);
    u.y = packh2(W[(k0 + 2) * kU + n], W[(k0 + 3) * kU + n]);
    u.z = packh2(W[(k0 + 4) * kU + n], W[(k0 + 5) * kU + n]);
    u.w = packh2(W[(k0 + 6) * kU + n], W[(k0 + 7) * kU + n]);
    wfrag[idx] = u;
}

__global__ __launch_bounds__(256) void convert_pk(
    const float* __restrict__ oW, const float* __restrict__ tW,
    const float* __restrict__ yW, unsigned* __restrict__ wpk)
{
    const int idx = blockIdx.x * 256 + threadIdx.x;   // 3*32768
    const int mat = idx >> 15;
    const int r   = idx & (kMatU32 - 1);
    const int kp  = r >> 8;
    const int j   = r & 255;
    const float* W = mat == 0 ? oW : mat == 1 ? tW : yW;
    wpk[idx] = packh2(W[(2 * kp) * kU + j], W[(2 * kp + 1) * kU + j]);
}

// ---------------------------------------------------------------------------
// Phase 1: sequential recurrence, fully weight-resident per CU.
// 16 blocks x 512 threads (8 waves). 16 batch rows per block (M=16).
// Wave w owns output cols [32w, 32w+32) = tiles nt0=2w, nt1=2w+1.
// Resident: hU in LDS (128 KB, B-frags); fW,iW,cW in VGPRs (192/wave).
// h/h1 tiles in frag-linear LDS (conflict-free ds_read_b128). 2 barriers/step.
// NO oW here: phase 2 computes o. Output: packed u32 (h fp16 | h1 fp16 << 16).
// ---------------------------------------------------------------------------
__global__ __launch_bounds__(512, 2) void rnn_phase1(
    const int* __restrict__ z,
    const float* __restrict__ hW, const float* __restrict__ hb,
    const float* __restrict__ fb, const float* __restrict__ ib,
    const float* __restrict__ cb,
    const float* __restrict__ h0,
    const uint4* __restrict__ wfrag,
    unsigned* __restrict__ outu)
{
    extern __shared__ __align__(16) char smem[];
    uint4* hUl  = (uint4*)smem;                // 131072 B
    char*  h1Ab = smem + 131072;               // 8192 B
    char*  hAb  = smem + 139264;               // 8192 B

    const int tid  = threadIdx.x;
    const int w    = tid >> 6;
    const int lane = tid & 63;
    const int m16  = lane & 15;
    const int g    = lane >> 4;
    const int b0   = blockIdx.x * 16;
    const int nt0  = 2 * w, nt1 = nt0 + 1;
    const int c0   = nt0 * 16 + m16;
    const int c1   = c0 + 16;

    // one-time: hU into LDS
    for (int i = tid; i < 8192; i += 512) hUl[i] = wfrag[i];

    // register-resident gate weights (own 2 col tiles)
    f16x8 wf0[8], wf1[8], wi0[8], wi1[8], wc0[8], wc1[8];
    #pragma unroll
    for (int kt = 0; kt < 8; ++kt) {
        wf0[kt] = __builtin_bit_cast(f16x8, wfrag[ 8192 + (nt0 * 8 + kt) * 64 + lane]);
        wf1[kt] = __builtin_bit_cast(f16x8, wfrag[ 8192 + (nt1 * 8 + kt) * 64 + lane]);
        wi0[kt] = __builtin_bit_cast(f16x8, wfrag[16384 + (nt0 * 8 + kt) * 64 + lane]);
        wi1[kt] = __builtin_bit_cast(f16x8, wfrag[16384 + (nt1 * 8 + kt) * 64 + lane]);
        wc0[kt] = __builtin_bit_cast(f16x8, wfrag[24576 + (nt0 * 8 + kt) * 64 + lane]);
        wc1[kt] = __builtin_bit_cast(f16x8, wfrag[24576 + (nt1 * 8 + kt) * 64 + lane]);
    }

    const float hb0 = hb[c0], hb1 = hb[c1];
    const float fb0 = fb[c0], fb1 = fb[c1];
    const float ib0 = ib[c0], ib1 = ib[c1];
    const float cb0 = cb[c0], cb1 = cb[c1];

    // h1 master fp32 (rows 4g+r, cols c0/c1)
    float h1m0[4], h1m1[4];
    {
        const float h00 = h0[c0], h01 = h0[c1];
        #pragma unroll
        for (int r = 0; r < 4; ++r) { h1m0[r] = h00; h1m1[r] = h01; }
    }
    // init h1A tile
    for (int i = tid; i < 16 * kU; i += 512) {
        const int m = i >> 8, k = i & 255;
        *(_Float16*)(h1Ab + afrag_byte(m, k)) = (_Float16)h0[k];
    }
    __syncthreads();

    unsigned obase[4];
    #pragma unroll
    for (int r = 0; r < 4; ++r)
        obase[r] = (unsigned)((b0 + 4 * g + r) * kS) * kU + c0;

    int zidx[4] = {0, 0, 0, 0};
    int znew[4] = {0, 0, 0, 0};

    for (int t = 0; t < kS; ++t) {
        // hW gathers for this step (consumed after hU mfma chain)
        float e0[4], e1[4];
        #pragma unroll
        for (int r = 0; r < 4; ++r) {
            const float* hwr = hW + (size_t)zidx[r] * kU;
            e0[r] = hwr[c0];
            e1[r] = hwr[c1];
        }
        // prefetch z col t (forms zidx for step t+1)
        if (t < kS - 1) {
            #pragma unroll
            for (int r = 0; r < 4; ++r)
                znew[r] = z[(b0 + 4 * g + r) * kS + t];
        }

        // a = h1 @ hU
        f32x4 a0 = {0.f, 0.f, 0.f, 0.f}, a1 = {0.f, 0.f, 0.f, 0.f};
        #pragma unroll
        for (int kt = 0; kt < 8; ++kt) {
            const f16x8 A = *(const f16x8*)(h1Ab + kt * 1024 + lane * 16);
            a0 = __builtin_amdgcn_mfma_f32_16x16x32_f16(
                A, __builtin_bit_cast(f16x8, hUl[(nt0 * 8 + kt) * 64 + lane]), a0, 0, 0, 0);
            a1 = __builtin_amdgcn_mfma_f32_16x16x32_f16(
                A, __builtin_bit_cast(f16x8, hUl[(nt1 * 8 + kt) * 64 + lane]), a1, 0, 0, 0);
        }

        // h = tanh(a + emb + hb) -> hA tile (and keep for output pack)
        float hv0[4], hv1[4];
        #pragma unroll
        for (int r = 0; r < 4; ++r) {
            hv0[r] = tanh_fast(a0[r] + e0[r] + hb0);
            hv1[r] = tanh_fast(a1[r] + e1[r] + hb1);
            const int m = 4 * g + r;
            *(_Float16*)(hAb + afrag_byte(m, c0)) = (_Float16)hv0[r];
            *(_Float16*)(hAb + afrag_byte(m, c1)) = (_Float16)hv1[r];
        }
        __syncthreads();   // barrier 1: hA complete; h1A reads done

        // gates f,i,c (register B-frags)
        f32x4 F0 = {0.f,0.f,0.f,0.f}, F1 = {0.f,0.f,0.f,0.f};
        f32x4 I0 = {0.f,0.f,0.f,0.f}, I1 = {0.f,0.f,0.f,0.f};
        f32x4 C0 = {0.f,0.f,0.f,0.f}, C1 = {0.f,0.f,0.f,0.f};
        #pragma unroll
        for (int kt = 0; kt < 8; ++kt) {
            const f16x8 A = *(const f16x8*)(hAb + kt * 1024 + lane * 16);
            F0 = __builtin_amdgcn_mfma_f32_16x16x32_f16(A, wf0[kt], F0, 0, 0, 0);
            F1 = __builtin_amdgcn_mfma_f32_16x16x32_f16(A, wf1[kt], F1, 0, 0, 0);
            I0 = __builtin_amdgcn_mfma_f32_16x16x32_f16(A, wi0[kt], I0, 0, 0, 0);
            I1 = __builtin_amdgcn_mfma_f32_16x16x32_f16(A, wi1[kt], I1, 0, 0, 0);
            C0 = __builtin_amdgcn_mfma_f32_16x16x32_f16(A, wc0[kt], C0, 0, 0, 0);
            C1 = __builtin_amdgcn_mfma_f32_16x16x32_f16(A, wc1[kt], C1, 0, 0, 0);
        }

        // update h1, pack (h, h1) output, refresh h1A tile
        const unsigned tOff = (unsigned)t * kU;
        #pragma unroll
        for (int r = 0; r < 4; ++r) {
            const int m = 4 * g + r;
            {
                const float ff = sigm(F0[r] + fb0);
                const float ii = sigm(I0[r] + ib0);
                const float cc = tanh_fast(C0[r] + cb0);
                h1m0[r] = h1m0[r] * ff + cc * ii;
                outu[obase[r] + tOff] = packh2(hv0[r], h1m0[r]);
                *(_Float16*)(h1Ab + afrag_byte(m, c0)) = (_Float16)h1m0[r];
            }
            {
                const float ff = sigm(F1[r] + fb1);
                const float ii = sigm(I1[r] + ib1);
                const float cc = tanh_fast(C1[r] + cb1);
                h1m1[r] = h1m1[r] * ff + cc * ii;
                outu[obase[r] + tOff + 16] = packh2(hv1[r], h1m1[r]);
                *(_Float16*)(h1Ab + afrag_byte(m, c1)) = (_Float16)h1m1[r];
            }
        }
        #pragma unroll
        for (int r = 0; r < 4; ++r) zidx[r] = znew[r] + 1;
        __syncthreads();   // barrier 2: h1A refreshed
    }
}

// ---------------------------------------------------------------------------
// Phase 2: output head. 8192 blocks x 256 threads, 16 rows/block.
// Reads packed (h,h1); computes o = sigm(h@oW+ob), g = o*h1,
// t = tanh(g@tW+tb), y = softmax(t@yW+yb). In-place on d_out.
// ---------------------------------------------------------------------------
__global__ __launch_bounds__(256) void rnn_phase2(
    const float* __restrict__ ob_, const float* __restrict__ tb,
    const float* __restrict__ yb,
    const unsigned* __restrict__ wpk,
    float* __restrict__ out)
{
    __shared__ unsigned pkl[16][kU];        // packed (h,h1) staging (16 KB)
    __shared__ unsigned xpk[16][kU / 2];    // packed pairs: h -> g -> t (8 KB)
    __shared__ float    lg[16][kU];         // logits (16 KB)

    const unsigned* __restrict__ oWpk = wpk;
    const unsigned* __restrict__ tWpk = wpk + kMatU32;
    const unsigned* __restrict__ yWpk = wpk + 2 * kMatU32;

    const int c = threadIdx.x;
    const size_t rowbase = (size_t)blockIdx.x * 16;
    unsigned* outu = (unsigned*)out;

    {
        const uint4* src = (const uint4*)(outu + rowbase * kU);
        uint4* dst = (uint4*)&pkl[0][0];
        #pragma unroll
        for (int i = 0; i < 4; ++i) dst[i * 256 + c] = src[i * 256 + c];
    }
    __syncthreads();

    // h packed pairs from low halves
    #pragma unroll
    for (int i = 0; i < 8; ++i) {
        const int flat = i * 256 + c;
        const int r = flat >> 7, kp = flat & 127;
        xpk[r][kp] = (pkl[r][2 * kp] & 0xFFFFu) | (pkl[r][2 * kp + 1] << 16);
    }
    __syncthreads();

    float acc[16];

    // ---- o = sigm(h @ oW + ob) ----
    {
        const float obc = ob_[c];
        #pragma unroll
        for (int r = 0; r < 16; ++r) acc[r] = obc;
    }
    #pragma unroll 2
    for (int kp4 = 0; kp4 < 32; ++kp4) {
        const unsigned w0 = oWpk[(4 * kp4 + 0) * kU + c];
        const unsigned w1 = oWpk[(4 * kp4 + 1) * kU + c];
        const unsigned w2 = oWpk[(4 * kp4 + 2) * kU + c];
        const unsigned w3 = oWpk[(4 * kp4 + 3) * kU + c];
        #pragma unroll
        for (int r = 0; r < 16; ++r) {
            const uint4 x = *(const uint4*)&xpk[r][4 * kp4];
            acc[r] = dot2(w0, x.x, acc[r]);
            acc[r] = dot2(w1, x.y, acc[r]);
            acc[r] = dot2(w2, x.z, acc[r]);
            acc[r] = dot2(w3, x.w, acc[r]);
        }
    }
    __syncthreads();   // all h-pair reads done

    // g = o * h1 ; repack pairs
    #pragma unroll
    for (int r = 0; r < 16; ++r) {
        const f16x2 pr = __builtin_bit_cast(f16x2, pkl[r][c]);
        const float gv = sigm(acc[r]) * (float)pr.y;
        const float gh = __shfl_down(gv, 1, 64);
        if ((c & 1) == 0) xpk[r][c >> 1] = packh2(gv, gh);
    }
    __syncthreads();

    // ---- t = tanh(g @ tW + tb) ----
    {
        const float tbc = tb[c];
        #pragma unroll
        for (int r = 0; r < 16; ++r) acc[r] = tbc;
    }
    #pragma unroll 2
    for (int kp4 = 0; kp4 < 32; ++kp4) {
        const unsigned w0 = tWpk[(4 * kp4 + 0) * kU + c];
        const unsigned w1 = tWpk[(4 * kp4 + 1) * kU + c];
        const unsigned w2 = tWpk[(4 * kp4 + 2) * kU + c];
        const unsigned w3 = tWpk[(4 * kp4 + 3) * kU + c];
        #pragma unroll
        for (int r = 0; r < 16; ++r) {
            const uint4 x = *(const uint4*)&xpk[r][4 * kp4];
            acc[r] = dot2(w0, x.x, acc[r]);
            acc[r] = dot2(w1, x.y, acc[r]);
            acc[r] = dot2(w2, x.z, acc[r]);
            acc[r] = dot2(w3, x.w, acc[r]);
        }
    }
    __syncthreads();

    #pragma unroll
    for (int r = 0; r < 16; ++r) {
        const float tv = tanh_fast(acc[r]);
        const float th = __shfl_down(tv, 1, 64);
        if ((c & 1) == 0) xpk[r][c >> 1] = packh2(tv, th);
    }
    __syncthreads();

    // ---- logits = t @ yW + yb ----
    {
        const float ybc = yb[c];
        #pragma unroll
        for (int r = 0; r < 16; ++r) acc[r] = ybc;
    }
    #pragma unroll 2
    for (int kp4 = 0; kp4 < 32; ++kp4) {
        const unsigned w0 = yWpk[(4 * kp4 + 0) * kU + c];
        const unsigned w1 = yWpk[(4 * kp4 + 1) * kU + c];
        const unsigned w2 = yWpk[(4 * kp4 + 2) * kU + c];
        const unsigned w3 = yWpk[(4 * kp4 + 3) * kU + c];
        #pragma unroll
        for (int r = 0; r < 16; ++r) {
            const uint4 x = *(const uint4*)&xpk[r][4 * kp4];
            acc[r] = dot2(w0, x.x, acc[r]);
            acc[r] = dot2(w1, x.y, acc[r]);
            acc[r] = dot2(w2, x.z, acc[r]);
            acc[r] = dot2(w3, x.w, acc[r]);
        }
    }

    #pragma unroll
    for (int r = 0; r < 16; ++r) lg[r][c] = acc[r];
    __syncthreads();

    // softmax: 4 waves x 4 rows each
    const int wv = c >> 6, lane = c & 63;
    for (int q = 0; q < 4; ++q) {
        const int r = wv * 4 + q;
        const float4 v = *(const float4*)&lg[r][lane * 4];
        float m = fmaxf(fmaxf(v.x, v.y), fmaxf(v.z, v.w));
        #pragma unroll
        for (int off = 32; off > 0; off >>= 1) m = fmaxf(m, __shfl_xor(m, off, 64));
        const float e0 = __expf(v.x - m), e1 = __expf(v.y - m);
        const float e2 = __expf(v.z - m), e3 = __expf(v.w - m);
        float s = e0 + e1 + e2 + e3;
        #pragma unroll
        for (int off = 32; off > 0; off >>= 1) s += __shfl_xor(s, off, 64);
        const float inv = 1.0f / s;
        float4 o4; o4.x = e0 * inv; o4.y = e1 * inv; o4.z = e2 * inv; o4.w = e3 * inv;
        *(float4*)&out[(rowbase + r) * kU + lane * 4] = o4;
    }
}

extern "C" void kernel_launch(void* const* d_in, const int* in_sizes, int n_in,
                              void* d_out, int out_size, void* d_ws, size_t ws_size,
                              hipStream_t stream) {
    const int*   z  = (const int*)d_in[0];
    const float* hW = (const float*)d_in[1];
    const float* hU = (const float*)d_in[2];
    const float* hb = (const float*)d_in[3];
    const float* fW = (const float*)d_in[4];
    const float* fb = (const float*)d_in[5];
    const float* iW = (const float*)d_in[6];
    const float* ib = (const float*)d_in[7];
    const float* cW = (const float*)d_in[8];
    const float* cb = (const float*)d_in[9];
    const float* oW = (const float*)d_in[10];
    const float* ob = (const float*)d_in[11];
    const float* tW = (const float*)d_in[12];
    const float* tb = (const float*)d_in[13];
    const float* yW = (const float*)d_in[14];
    const float* yb = (const float*)d_in[15];
    const float* h0 = (const float*)d_in[16];
    float* out = (float*)d_out;

    uint4*    wfrag = (uint4*)d_ws;                   // 4*8192 uint4 = 512 KB
    unsigned* wpk   = (unsigned*)d_ws + 4 * kMatU32;  // oW,tW,yW packed pairs

    // allow 144 KB dynamic LDS (idempotent host-side attribute)
    hipFuncSetAttribute((const void*)rnn_phase1,
                        hipFuncAttributeMaxDynamicSharedMemorySize, 147456);

    convert_frag<<<dim3(4 * 8192 / 256), dim3(256), 0, stream>>>(
        hU, fW, iW, cW, wfrag);
    convert_pk<<<dim3(3 * kMatU32 / 256), dim3(256), 0, stream>>>(
        oW, tW, yW, wpk);
    rnn_phase1<<<dim3(kB / 16), dim3(512), 147456, stream>>>(
        z, hW, hb, fb, ib, cb, h0, wfrag, (unsigned*)out);
    rnn_phase2<<<dim3((kB * kS) / 16), dim3(256), 0, stream>>>(
        ob, tb, yb, wpk, out);
}